// Round 6
// baseline (39458.640 us; speedup 1.0000x reference)
//
#include <hip/hip_runtime.h>
#include <stdint.h>
#include <stddef.h>

// MambaBlock on MI355X (gfx950).
// out = OutProj( scan_t( s_t = tanh(A(g_t*s_{t-1}) + v_t) ) )
// with v = ((1-g)*inp)@A^T + inp@B^T hoisted into one K=2048 GEMM.
//
// Round 8: TAG-IN-DATA TRANSPORT + POLLER DETECTION (hop-count cut).
// Round-5 falsified the atomic theory (byte counters identical): the
// exchange already lives at the LLC; each hop ~0.7us. So cut HOPS:
//   producer: ONE fire-and-forget tagged store per lane {tag,d0,d1,tag}
//             (16B atomic unit) -- no vmcnt(0) drain, no barrier, no flag
//             (saves ~1.4-1.7us of serial chain per step).
//   consumer: wave0 polls 64 REPRESENTATIVE data slots (lane0-slot of each
//             producer wave, 64 contiguous lines; 2-deep pipelined poll),
//             releases siblings via LDS; then round-3's proven tagged-load
//             + validate machinery (retry now RARE since poll confirmed
//             representatives; bounded 256 so a protocol bug -> wrong
//             answer report, never a hang).
// Leftover stores are drained at the TOP of the next step where the drain
// overlaps waiting for other producers (off the critical path); this also
// keeps the staged vmcnt(28-4c)/WAITV8 load counts exact.
// Signature if theory holds: WRITE ~198MB (m bytes DOUBLE while time drops),
// FETCH ~500MB, scan ~17-19ms.

#define DIM   1024
#define SEQ   4096
#define NB    8
#define NTOK  (NB*SEQ)   // 32768

typedef __attribute__((ext_vector_type(8))) short          short8;
typedef __attribute__((ext_vector_type(4))) float          float4v;
typedef __attribute__((ext_vector_type(4))) int            int4v;
typedef __attribute__((ext_vector_type(4))) unsigned short ushort4v;

__device__ __forceinline__ unsigned short f2b(float f) {
  union { float f; unsigned int u; } v; v.f = f;
  return (unsigned short)((v.u + 0x7FFFu + ((v.u >> 16) & 1u)) >> 16);   // RNE
}
__device__ __forceinline__ float b2f(unsigned short h) {
  union { unsigned int u; float f; } v; v.u = ((unsigned int)h) << 16;
  return v.f;
}

// ---------------------------------------------------------------- small prep
__global__ void cast_bf16(const float* __restrict__ src,
                          unsigned short* __restrict__ dst, int n) {
  int i4 = (blockIdx.x * blockDim.x + threadIdx.x) * 4;
  if (i4 >= n) return;
  float4v v = *(const float4v*)(src + i4);
  ushort4v o;
  o[0] = f2b(v[0]); o[1] = f2b(v[1]); o[2] = f2b(v[2]); o[3] = f2b(v[3]);
  *(ushort4v*)(dst + i4) = o;
}

// Wcat[e][0:1024] = B[e][:], Wcat[e][1024:2048] = A[e][:]; Ab = bf16(A)
__global__ void build_wcat(const float* __restrict__ Bm, const float* __restrict__ A,
                           unsigned short* __restrict__ Wcat,
                           unsigned short* __restrict__ Ab) {
  int i4 = (blockIdx.x * 256 + threadIdx.x) * 4;       // 0..1048572
  int e = i4 >> 10, d = i4 & 1023;
  float4v bv = *(const float4v*)(Bm + i4);
  float4v av = *(const float4v*)(A + i4);
  ushort4v bb, ab;
  #pragma unroll
  for (int r = 0; r < 4; r++) { bb[r] = f2b(bv[r]); ab[r] = f2b(av[r]); }
  *(ushort4v*)(Wcat + (size_t)e * 2048 + d) = bb;
  *(ushort4v*)(Wcat + (size_t)e * 2048 + 1024 + d) = ab;
  *(ushort4v*)(Ab + i4) = ab;
}

__global__ void zero_u32(unsigned int* __restrict__ p, int n) {
  int i = blockIdx.x * 256 + threadIdx.x;
  if (i < n) p[i] = 0u;
}

// ---------------------------------------------------------------- GEMM (NT)
// C[m,n] = sum_k Ag[m,k]*Bg[n,k]  (both K-contiguous), 128x128 tile, BK=64.
// LDS rows padded to 72 elems -> conflict-free b128.
// EPI: 0 inp->inpq[:, :1024] bf16 | 1 gate->gscan bf16 + q->inpq[:,1024:]
//      2 v->fp32 [t*8+b][e]       | 3 out->fp32 [b*4096+t][e]
template<int EPI>
__global__ __launch_bounds__(256, 2)
void gemm_nt(const unsigned short* __restrict__ Ag, int lda,
             const unsigned short* __restrict__ Bg, int ldb,
             int K,
             const float* __restrict__ bias,
             void* __restrict__ out0,
             unsigned short* __restrict__ out1,
             const unsigned short* __restrict__ aux) {
  __shared__ unsigned short sA[128 * 72];
  __shared__ unsigned short sB[128 * 72];
  const int tid  = threadIdx.x;
  const int lane = tid & 63;
  const int wave = tid >> 6;
  const int wm = wave & 1, wn = wave >> 1;
  const int m0 = blockIdx.x * 128;
  const int n0 = blockIdx.y * 128;
  const int q  = lane >> 4;
  const int ln = lane & 15;

  float4v acc[4][4];
  const float4v fz = {0.f, 0.f, 0.f, 0.f};
  #pragma unroll
  for (int i = 0; i < 4; i++)
    #pragma unroll
    for (int j = 0; j < 4; j++) acc[i][j] = fz;

  for (int kk = 0; kk < K; kk += 64) {
    __syncthreads();                       // protect LDS reuse
    #pragma unroll
    for (int s = 0; s < 4; s++) {          // stage 128x64 of A and B
      int chunk = tid + s * 256;           // 0..1023 : row*8 + c
      int row = chunk >> 3, c = chunk & 7;
      int4v va = *(const int4v*)(Ag + (size_t)(m0 + row) * lda + kk + c * 8);
      int4v vb = *(const int4v*)(Bg + (size_t)(n0 + row) * ldb + kk + c * 8);
      *(int4v*)(sA + row * 72 + c * 8) = va;
      *(int4v*)(sB + row * 72 + c * 8) = vb;
    }
    __syncthreads();
    #pragma unroll
    for (int ks = 0; ks < 64; ks += 32) {
      short8 af[4], bf[4];
      #pragma unroll
      for (int i = 0; i < 4; i++)
        af[i] = *(const short8*)(sA + (wm * 64 + i * 16 + ln) * 72 + ks + q * 8);
      #pragma unroll
      for (int j = 0; j < 4; j++)
        bf[j] = *(const short8*)(sB + (wn * 64 + j * 16 + ln) * 72 + ks + q * 8);
      #pragma unroll
      for (int i = 0; i < 4; i++)
        #pragma unroll
        for (int j = 0; j < 4; j++)
          acc[i][j] = __builtin_amdgcn_mfma_f32_16x16x32_bf16(af[i], bf[j], acc[i][j], 0, 0, 0);
    }
  }

  #pragma unroll
  for (int j = 0; j < 4; j++) {
    const int gn = n0 + wn * 64 + j * 16 + ln;      // N index (feature e)
    const float bval = (EPI == 2) ? 0.f : bias[gn];
    #pragma unroll
    for (int i = 0; i < 4; i++) {
      const int gm = m0 + wm * 64 + i * 16 + q * 4; // M index (token row)
      #pragma unroll
      for (int r = 0; r < 4; r++) {
        const int row = gm + r;
        float vv = acc[i][j][r] + bval;
        if constexpr (EPI == 0) {
          ((unsigned short*)out0)[(size_t)row * 2048 + gn] = f2b(vv);
        } else if constexpr (EPI == 1) {
          float g = 1.f / (1.f + __expf(-vv));
          int t = row & (SEQ - 1), b = row >> 12;   // token row = b*SEQ + t
          ((unsigned short*)out0)[(size_t)(t * NB + b) * DIM + gn] = f2b(g);
          float iv = b2f(aux[(size_t)row * 2048 + gn]);
          out1[(size_t)row * 2048 + 1024 + gn] = f2b((1.f - g) * iv);
        } else if constexpr (EPI == 2) {
          int t = row & (SEQ - 1), b = row >> 12;
          ((float*)out0)[(size_t)(t * NB + b) * DIM + gn] = vv;
        } else {                                    // row = t*8 + b
          int b = row & 7, t = row >> 3;
          ((float*)out0)[(size_t)(b * SEQ + t) * DIM + gn] = vv;
        }
      }
    }
  }
}

// ---------------------------------------------------------------- scan helpers
// Tagged slot layout: one 16B slot per 4 bf16 m-values:
//   { tag(u32), data0(2xbf16), data1(2xbf16), tag(u32) }, tag = step index.
// Slot for elem (b, e): byte (b*1024 + e)*4 in a 32KB parity block (2 blocks).
// Consumer lane (q,bcl), fragment ks: slots at bcl*4096 + ks*128 + q*32 (+16).
// Representative of producer wave w = slot (b=0, e=w*16) = byte w*64.

template<int G>
__device__ __forceinline__ void issue8(const char* cb, int4v* s) {
  #pragma unroll
  for (int j = 0; j < 4; j++) {
    asm volatile("global_load_dwordx4 %0, %1, off offset:%2 sc0 sc1"
                 : "=v"(s[2 * j])     : "v"(cb), "n"(G * 512 + j * 128));
    asm volatile("global_load_dwordx4 %0, %1, off offset:%2 sc0 sc1"
                 : "=v"(s[2 * j + 1]) : "v"(cb), "n"(G * 512 + j * 128 + 16));
  }
}

#define WAITV8(s)                                                   \
  asm volatile("s_waitcnt vmcnt(8)"                                 \
    : "+v"((s)[0]), "+v"((s)[1]), "+v"((s)[2]), "+v"((s)[3]),       \
      "+v"((s)[4]), "+v"((s)[5]), "+v"((s)[6]), "+v"((s)[7]) :: "memory")
#define WAITV0(s)                                                   \
  asm volatile("s_waitcnt vmcnt(0)"                                 \
    : "+v"((s)[0]), "+v"((s)[1]), "+v"((s)[2]), "+v"((s)[3]),       \
      "+v"((s)[4]), "+v"((s)[5]), "+v"((s)[6]), "+v"((s)[7]) :: "memory")

// Wait for group G, verify 16 tag words (retry stale, bounded), 4 MFMAs.
// Issues group G+1 first so its loads overlap G's validation+compute.
// With the representative poll done first, retries are rare.
template<int G>
__device__ __forceinline__ void consume_group(const char* cb, int4v* sl,
                                              const short8* af, float4v* aa,
                                              const int tgt) {
  int4v* sg = sl + ((G & 1) * 8);
  if constexpr (G < 7) issue8<G + 1>(cb, sl + (((G + 1) & 1) * 8));
  if constexpr (G < 7) { WAITV8(sg); } else { WAITV0(sg); }
  int tries = 0;
  for (;;) {
    int bad = 0;
    #pragma unroll
    for (int j = 0; j < 4; j++) {
      bad |= (sg[2 * j][0] ^ tgt) | (sg[2 * j][3] ^ tgt) |
             (sg[2 * j + 1][0] ^ tgt) | (sg[2 * j + 1][3] ^ tgt);
    }
    if (__all(bad == 0) || ++tries > 256) break;   // bounded: bug -> wrong, not hung
    issue8<G>(cb, sg);
    WAITV0(sg);
  }
  #pragma unroll
  for (int j = 0; j < 4; j++) {
    int4v fd;
    fd[0] = sg[2 * j][1];     fd[1] = sg[2 * j][2];
    fd[2] = sg[2 * j + 1][1]; fd[3] = sg[2 * j + 1][2];
    union { int4v i; short8 s; } cv; cv.i = fd;
    aa[j] = __builtin_amdgcn_mfma_f32_16x16x32_bf16(af[4 * G + j], cv.s, aa[j], 0, 0, 0);
  }
}

// ---------------------------------------------------------------- scan
// 16 WGs x 256 thr = 64 waves; wave gw owns e-rows [16*gw, 16*gw+16).
// Per step: vmcnt(0) leftover drain (overlaps others' stores landing) ->
// [wave0: 2-deep pipelined poll of 64 representative slots -> LDS release ->
// drain | others: LDS spin] -> next-step v/g prefetch (asm, oldest) ->
// 8 pipelined tagged groups (validate + 4 MFMAs each) -> tanh epi ->
// sb store (cached) + ONE tagged m-store (fire-and-forget). No barrier,
// no flags, no producer drain.
__global__ __launch_bounds__(256, 1)
void scan_kernel(const unsigned short* __restrict__ Ab,     // [1024][1024] bf16
                 const unsigned short* __restrict__ gscan,  // [t*8+b][1024] bf16
                 const float* __restrict__ vflat,           // [t*8+b][1024] f32
                 unsigned short* __restrict__ sb,           // [t*8+b][1024] bf16
                 char* __restrict__ mtag) {                 // [2][32KB] tagged slots
  const int tid  = threadIdx.x;
  const int lane = tid & 63;
  const int wave = tid >> 6;
  const int gw   = blockIdx.x * 4 + wave;    // 0..63
  const int e0   = gw * 16;
  const int q    = lane >> 4;
  const int ln   = lane & 15;
  const int bcl  = ln & 7;                   // clamped batch (cols 8-15 unused)
  const bool active = (ln < 8);
  const int eb = e0 + q * 4;

  __shared__ volatile int sready;
  if (tid == 0) sready = -1;
  __syncthreads();

  short8 af[32];                             // A rows in registers (128 VGPRs)
  #pragma unroll
  for (int ks = 0; ks < 32; ks++)
    af[ks] = *(const short8*)(Ab + (size_t)(e0 + ln) * 1024 + ks * 32 + q * 8);

  const int cload = bcl * 4096 + q * 32;            // consumer lane offset
  const int pslot = (bcl * 1024 + eb) * 4;          // producer slot offset
  const float4v fz = {0.f, 0.f, 0.f, 0.f};

  // prologue: prefetch v_0 and g_1 (consumed at t=0)
  float4v vv = fz;
  ushort4v g4 = {0, 0, 0, 0};
  if (active) {
    vv = *(const float4v*)(vflat + (size_t)bcl * DIM + eb);
    g4 = *(const ushort4v*)(gscan + (size_t)(NB + bcl) * DIM + eb);
  }

  for (int t = 0; t < SEQ; t++) {
    // drain leftovers (prev m/sb stores, poll residue) OFF the critical
    // path: overlaps waiting for other producers' stores to land.
    asm volatile("s_waitcnt vmcnt(0)" ::: "memory");

    // ---- detection: wave0 polls 64 representative slots (2-deep pipeline)
    if (wave == 0) {
      const char* fp = mtag + ((t & 1) << 15) + lane * 64;
      int4v p0, p1;
      asm volatile("global_load_dwordx4 %0, %1, off sc0 sc1"
                   : "=&v"(p0) : "v"(fp) : "memory");
      asm volatile("global_load_dwordx4 %0, %1, off sc0 sc1"
                   : "=&v"(p1) : "v"(fp) : "memory");
      for (;;) {
        asm volatile("s_waitcnt vmcnt(1)" : "+v"(p0) :: "memory");
        if (__all((int)(p0[0] == t && p0[3] == t))) break;
        asm volatile("global_load_dwordx4 %0, %1, off sc0 sc1"
                     : "=&v"(p0) : "v"(fp) : "memory");
        asm volatile("s_waitcnt vmcnt(1)" : "+v"(p1) :: "memory");
        if (__all((int)(p1[0] == t && p1[3] == t))) break;
        asm volatile("global_load_dwordx4 %0, %1, off sc0 sc1"
                     : "=&v"(p1) : "v"(fp) : "memory");
      }
      sready = t;                            // release siblings FIRST
      asm volatile("s_waitcnt vmcnt(0)" ::: "memory");  // drain leftover poll
    } else {
      while (sready < t) { }                 // LDS spin (local)
    }

    // ---- prefetch NEXT step's v/g (plain cached, oldest ops this step)
    const int tn = (t + 1 < SEQ) ? t + 1 : SEQ - 1;
    const int tg = (t + 2 < SEQ) ? t + 2 : SEQ - 1;
    const float* vp = vflat + (size_t)(tn * NB + bcl) * DIM + eb;
    const unsigned short* gp = gscan + (size_t)(tg * NB + bcl) * DIM + eb;
    float4v vv_n;
    ushort4v g4_n;
    asm volatile("global_load_dwordx4 %0, %1, off" : "=v"(vv_n) : "v"(vp));
    asm volatile("global_load_dwordx2 %0, %1, off" : "=v"(g4_n) : "v"(gp));

    // ---- tagged m_t loads: 8 pipelined groups, validate + MFMA
    const char* cb = mtag + ((t & 1) << 15) + cload;
    int4v sl[16];                            // 2 groups in flight (64 VGPRs)
    issue8<0>(cb, sl);
    float4v aa[4] = {fz, fz, fz, fz};
    consume_group<0>(cb, sl, af, aa, t);
    consume_group<1>(cb, sl, af, aa, t);
    consume_group<2>(cb, sl, af, aa, t);
    consume_group<3>(cb, sl, af, aa, t);
    consume_group<4>(cb, sl, af, aa, t);
    consume_group<5>(cb, sl, af, aa, t);
    consume_group<6>(cb, sl, af, aa, t);
    consume_group<7>(cb, sl, af, aa, t);

    if (active) {
      size_t rowoff = (size_t)(t * NB + bcl) * DIM + eb;
      float sv[4];
      #pragma unroll
      for (int r = 0; r < 4; r++) {
        float xx = aa[0][r] + aa[1][r] + aa[2][r] + aa[3][r] + vv[r];
        float ex = __expf(-2.f * fabsf(xx));
        float th = (1.f - ex) / (1.f + ex);
        sv[r] = copysignf(th, xx);
      }
      ushort4v sp;
      #pragma unroll
      for (int r = 0; r < 4; r++) sp[r] = f2b(sv[r]);
      *(ushort4v*)(sb + rowoff) = sp;                       // state for out-proj
      if (t < SEQ - 1) {                                    // m_{t+1} = g*s, tagged
        int d0 = (int)((unsigned int)f2b(b2f(g4[0]) * sv[0]) |
                       ((unsigned int)f2b(b2f(g4[1]) * sv[1]) << 16));
        int d1 = (int)((unsigned int)f2b(b2f(g4[2]) * sv[2]) |
                       ((unsigned int)f2b(b2f(g4[3]) * sv[3]) << 16));
        int4v st;
        st[0] = t + 1; st[1] = d0; st[2] = d1; st[3] = t + 1;
        char* mp = mtag + (((t + 1) & 1) << 15) + pslot;
        // ONE fire-and-forget publish: freshness rides with the data.
        asm volatile("global_store_dwordx4 %0, %1, off sc0 sc1"
                     :: "v"(mp), "v"(st) : "memory");
      }
    }

    vv = vv_n;                               // carry next step's operands
    g4 = g4_n;
  }
}

// ---------------------------------------------------------------- launch
extern "C" void kernel_launch(void* const* d_in, const int* in_sizes, int n_in,
                              void* d_out, int out_size, void* d_ws, size_t ws_size,
                              hipStream_t stream) {
  const float* x      = (const float*)d_in[0];
  const float* A      = (const float*)d_in[1];
  const float* Bm     = (const float*)d_in[2];
  const float* W_in   = (const float*)d_in[3];
  const float* b_in   = (const float*)d_in[4];
  const float* W_gate = (const float*)d_in[5];
  const float* b_gate = (const float*)d_in[6];
  const float* W_out  = (const float*)d_in[7];
  const float* b_out  = (const float*)d_in[8];

  char* ws = (char*)d_ws;
  // workspace layout (~281 MB total)
  unsigned short* xb      = (unsigned short*)(ws);                 // 64 MB (reused as sb)
  unsigned short* inpq    = (unsigned short*)(ws + 67108864);      // 128 MB [n][2048]
  unsigned short* gscan   = (unsigned short*)(ws + 201326592);     // 64 MB
  unsigned short* Wb_in   = (unsigned short*)(ws + 268435456);     // 2 MB
  unsigned short* Wb_gate = (unsigned short*)(ws + 270532608);     // 2 MB
  unsigned short* Wb_out  = (unsigned short*)(ws + 272629760);     // 2 MB
  unsigned short* Wcat    = (unsigned short*)(ws + 274726912);     // 4 MB [e][2048]
  unsigned short* Ab      = (unsigned short*)(ws + 278921216);     // 2 MB
  char*           mtag    = (char*)(ws + 281018368);               // 64 KB tagged slots
  float*          vflat   = (float*)d_out;          // v lives in d_out pre-scan
  unsigned short* sbuf    = xb;                     // states overwrite xb

  // prep
  cast_bf16<<<(33554432 / 4 + 255) / 256, 256, 0, stream>>>(x, xb, 33554432);
  cast_bf16<<<1024, 256, 0, stream>>>(W_in,   Wb_in,   1048576);
  cast_bf16<<<1024, 256, 0, stream>>>(W_gate, Wb_gate, 1048576);
  cast_bf16<<<1024, 256, 0, stream>>>(W_out,  Wb_out,  1048576);
  build_wcat<<<1024, 256, 0, stream>>>(Bm, A, Wcat, Ab);
  // zero tagged slots: tag 0 == valid m_0 = 0
  zero_u32<<<(16384 + 255) / 256, 256, 0, stream>>>((unsigned int*)mtag, 16384);

  dim3 grid(NTOK / 128, DIM / 128);
  // inp = x @ W_in^T + b_in
  gemm_nt<0><<<grid, 256, 0, stream>>>(xb, DIM, Wb_in, DIM, DIM, b_in,
                                       (void*)inpq, nullptr, nullptr);
  // g = sigmoid(inp @ W_gate^T + b_gate); q = (1-g)*inp
  gemm_nt<1><<<grid, 256, 0, stream>>>(inpq, 2048, Wb_gate, DIM, DIM, b_gate,
                                       (void*)gscan, inpq, inpq);
  // v = [inp, q] @ [B; A]^T   (K = 2048)
  gemm_nt<2><<<grid, 256, 0, stream>>>(inpq, 2048, Wcat, 2048, 2048, b_in,
                                       (void*)vflat, nullptr, nullptr);
  // sequential scan
  scan_kernel<<<16, 256, 0, stream>>>(Ab, gscan, vflat, sbuf, mtag);
  // out = states @ W_out^T + b_out  (with [t*8+b] -> [b*4096+t] permute)
  gemm_nt<3><<<grid, 256, 0, stream>>>(sbuf, DIM, Wb_out, DIM, DIM, b_out,
                                       (void*)d_out, nullptr, nullptr);
}